// Round 1
// baseline (655.894 us; speedup 1.0000x reference)
//
#include <hip/hip_runtime.h>

#define N_EDGES 1600000
#define N_NODES 50000
#define D_FEAT  32

// Copy the "out" input (accumulator base) into d_out, vectorized float4.
__global__ void init_out_kernel(const float4* __restrict__ out_in,
                                float4* __restrict__ out, int n4) {
    int i = blockIdx.x * blockDim.x + threadIdx.x;
    int stride = gridDim.x * blockDim.x;
    for (; i < n4; i += stride) out[i] = out_in[i];
}

// Scatter-add: 8 threads per edge, each thread handles one float4 (4 feats).
// src loads are perfectly coalesced (consecutive lanes -> consecutive float4).
// Atomics land in the 6.4 MB out buffer, which is L2/L3 resident.
__global__ void scatter_add_kernel(const float4* __restrict__ src,
                                   const int* __restrict__ index,
                                   float* __restrict__ out) {
    const int total = N_EDGES * 8;  // 8 float4 chunks per edge
    int t = blockIdx.x * blockDim.x + threadIdx.x;
    int stride = gridDim.x * blockDim.x;
    for (; t < total; t += stride) {
        int e = t >> 3;       // edge id
        int f = t & 7;        // float4 slot within the 32-feat row
        float4 v = src[t];    // src[e*8 + f]
        int node = index[e];  // 8 lanes of an edge read same value (cache broadcast)
        float* o = out + (size_t)node * D_FEAT + f * 4;
        atomicAdd(o + 0, v.x);
        atomicAdd(o + 1, v.y);
        atomicAdd(o + 2, v.z);
        atomicAdd(o + 3, v.w);
    }
}

extern "C" void kernel_launch(void* const* d_in, const int* in_sizes, int n_in,
                              void* d_out, int out_size, void* d_ws, size_t ws_size,
                              hipStream_t stream) {
    const float4* src   = (const float4*)d_in[0];
    const int*  index   = (const int*)d_in[1];
    const float4* outin = (const float4*)d_in[2];
    float* out          = (float*)d_out;

    // 1) out = out_input (zeros per setup, but semantically required; also
    //    clears the 0xAA poison each call).
    int n4 = out_size / 4;  // 1.6M floats -> 400K float4
    init_out_kernel<<<2048, 256, 0, stream>>>(outin, (float4*)out, n4);

    // 2) atomic scatter-add
    scatter_add_kernel<<<2048, 256, 0, stream>>>(src, index, out);
}

// Round 2
// 272.913 us; speedup vs baseline: 2.4033x; 2.4033x over previous
//
#include <hip/hip_runtime.h>

#define N_EDGES 1600000
#define N_NODES 50000
#define D_FEAT  32

// ---- workspace layout (bytes) ----
// offs: int[N_NODES+1] at 0   (doubles as counts during histogram)
// rank: int[N_EDGES]   at RANK_OFF
// perm: int[N_EDGES]   at PERM_OFF
#define OFFS_BYTES ((N_NODES + 1) * 4)
#define RANK_OFF   ((size_t)(((OFFS_BYTES + 255) / 256) * 256))
#define PERM_OFF   (RANK_OFF + (size_t)N_EDGES * 4)
#define WS_NEEDED  (PERM_OFF + (size_t)N_EDGES * 4)

__global__ void zero_counts_kernel(int* __restrict__ cnt) {
    int i = blockIdx.x * blockDim.x + threadIdx.x;
    if (i <= N_NODES) cnt[i] = 0;
}

// rank[e] = position of edge e within its node's segment (order nondeterministic,
// but fp32 sum within a ~32-edge segment stays far below the harness threshold).
__global__ void hist_rank_kernel(const int* __restrict__ index,
                                 int* __restrict__ cnt,
                                 int* __restrict__ rank) {
    int e = blockIdx.x * blockDim.x + threadIdx.x;
    int stride = gridDim.x * blockDim.x;
    for (; e < N_EDGES; e += stride)
        rank[e] = atomicAdd(&cnt[index[e]], 1);
}

// Single-block in-place exclusive scan: counts -> offsets, offs[N_NODES] = total.
__global__ __launch_bounds__(1024) void scan_offsets_kernel(int* __restrict__ cnt) {
    const int T = 1024;
    const int C = (N_NODES + T - 1) / T;  // 49 elements per thread
    __shared__ int part[T];
    int t = threadIdx.x;
    int base = t * C;
    // chunk sum
    int s = 0;
    for (int j = 0; j < C; ++j) {
        int i = base + j;
        if (i < N_NODES) s += cnt[i];
    }
    part[t] = s;
    __syncthreads();
    // inclusive Hillis-Steele scan over 1024 partials
    int v = s;
    for (int d = 1; d < T; d <<= 1) {
        int w = (t >= d) ? part[t - d] : 0;
        __syncthreads();
        v += w;
        part[t] = v;
        __syncthreads();
    }
    int run = v - s;  // exclusive prefix of this chunk
    for (int j = 0; j < C; ++j) {
        int i = base + j;
        if (i < N_NODES) {
            int c = cnt[i];
            cnt[i] = run;
            run += c;
        }
    }
    if (t == T - 1) cnt[N_NODES] = v;  // grand total = N_EDGES
}

__global__ void build_perm_kernel(const int* __restrict__ index,
                                  const int* __restrict__ offs,
                                  const int* __restrict__ rank,
                                  int* __restrict__ perm) {
    int e = blockIdx.x * blockDim.x + threadIdx.x;
    int stride = gridDim.x * blockDim.x;
    for (; e < N_EDGES; e += stride)
        perm[offs[index[e]] + rank[e]] = e;
}

// One 64-lane wave per node. lane = feat (0..31) + 32*half; the two halves
// process alternating edges of the segment, then combine via shfl_xor(32).
// src row loads are 128 B aligned contiguous; output write is one 128 B store.
__global__ void gather_sum_kernel(const float* __restrict__ src,
                                  const int* __restrict__ perm,
                                  const int* __restrict__ offs,
                                  const float* __restrict__ out_in,
                                  float* __restrict__ out) {
    int wave = threadIdx.x >> 6;            // 4 waves / 256-thread block
    int node = blockIdx.x * 4 + wave;
    if (node >= N_NODES) return;
    int lane = threadIdx.x & 63;
    int f = lane & 31;
    int h = lane >> 5;
    int start = offs[node];
    int end   = offs[node + 1];
    float acc = 0.f;
    for (int i = start + h; i < end; i += 2)
        acc += src[(size_t)perm[i] * D_FEAT + f];
    acc += __shfl_xor(acc, 32, 64);         // combine the two halves
    if (h == 0) {
        size_t o = (size_t)node * D_FEAT + f;
        out[o] = out_in[o] + acc;
    }
}

// ---- fallback (round-1 proven path) if ws is too small ----
__global__ void init_out_kernel(const float4* __restrict__ out_in,
                                float4* __restrict__ out, int n4) {
    int i = blockIdx.x * blockDim.x + threadIdx.x;
    int stride = gridDim.x * blockDim.x;
    for (; i < n4; i += stride) out[i] = out_in[i];
}
__global__ void scatter_add_kernel(const float4* __restrict__ src,
                                   const int* __restrict__ index,
                                   float* __restrict__ out) {
    const int total = N_EDGES * 8;
    int t = blockIdx.x * blockDim.x + threadIdx.x;
    int stride = gridDim.x * blockDim.x;
    for (; t < total; t += stride) {
        int e = t >> 3;
        int f = t & 7;
        float4 v = src[t];
        int node = index[e];
        float* o = out + (size_t)node * D_FEAT + f * 4;
        atomicAdd(o + 0, v.x);
        atomicAdd(o + 1, v.y);
        atomicAdd(o + 2, v.z);
        atomicAdd(o + 3, v.w);
    }
}

extern "C" void kernel_launch(void* const* d_in, const int* in_sizes, int n_in,
                              void* d_out, int out_size, void* d_ws, size_t ws_size,
                              hipStream_t stream) {
    const float* src    = (const float*)d_in[0];
    const int*   index  = (const int*)d_in[1];
    const float* out_in = (const float*)d_in[2];
    float* out          = (float*)d_out;

    if (ws_size < WS_NEEDED) {
        // fallback: atomic scatter (verified round 1)
        int n4 = out_size / 4;
        init_out_kernel<<<2048, 256, 0, stream>>>((const float4*)out_in, (float4*)out, n4);
        scatter_add_kernel<<<2048, 256, 0, stream>>>((const float4*)src, index, out);
        return;
    }

    char* ws = (char*)d_ws;
    int* offs = (int*)ws;                   // counts, then offsets
    int* rank = (int*)(ws + RANK_OFF);
    int* perm = (int*)(ws + PERM_OFF);

    zero_counts_kernel<<<(N_NODES + 256) / 256, 256, 0, stream>>>(offs);
    hist_rank_kernel<<<2048, 256, 0, stream>>>(index, offs, rank);
    scan_offsets_kernel<<<1, 1024, 0, stream>>>(offs);
    build_perm_kernel<<<2048, 256, 0, stream>>>(index, offs, rank, perm);
    gather_sum_kernel<<<(N_NODES + 3) / 4, 256, 0, stream>>>(src, perm, offs, out_in, out);
}